// Round 20
// baseline (145.691 us; speedup 1.0000x reference)
//
#include <hip/hip_runtime.h>
#include <math.h>

#define BB    2
#define LL    2048
#define DIM   1024
#define NH    16
#define DHD   64
#define NPER  16
#define NMEM  64
#define PFX   80      // NPER + NMEM
#define SS    2128    // PFX + LL
#define MQKV  (BB*SS) // 4256
#define NQKV  3072
#define MOUT  (BB*LL) // 4096

typedef __attribute__((ext_vector_type(4)))  float f32x4;
typedef __attribute__((ext_vector_type(16))) float f32x16;
typedef __attribute__((ext_vector_type(8)))  short bf16x8;
typedef unsigned short u16;
typedef unsigned int   u32;

union I4B8 { int4 i; bf16x8 v; };

__device__ __forceinline__ u16 f2bf(float x) {
    union { float f; u32 u; } v; v.f = x;
    return (u16)((v.u + 0x7fffu + ((v.u >> 16) & 1u)) >> 16);
}
__device__ __forceinline__ u32 cvtpk(float lo, float hi) {
    u32 r; asm("v_cvt_pk_bf16_f32 %0, %1, %2" : "=v"(r) : "v"(lo), "v"(hi));
    return r;
}
__device__ __forceinline__ void gload_lds16(const void* g, void* l) {
    __builtin_amdgcn_global_load_lds(
        (__attribute__((address_space(1))) void*)(g),
        (__attribute__((address_space(3))) void*)(l), 16, 0, 0);
}

#define BARRIER()  __builtin_amdgcn_s_barrier()
#define VMCNT0()   asm volatile("s_waitcnt vmcnt(0)")

// ---------------------------------------------------------------------------
// Prep: fp32 -> bf16 conversions + RoPE tables
// ---------------------------------------------------------------------------
__global__ __launch_bounds__(256)
void prep_kernel(const float* __restrict__ x,  const float* __restrict__ pe,
                 const float* __restrict__ me, const float* __restrict__ Wq,
                 const float* __restrict__ Wk, const float* __restrict__ Wv,
                 const float* __restrict__ Wo,
                 u16* __restrict__ xbf, u16* __restrict__ wqkv,
                 u16* __restrict__ wobf,
                 float* __restrict__ ropeC, float* __restrict__ ropeS)
{
    const int nthr = gridDim.x * blockDim.x;
    const int t0   = blockIdx.x * blockDim.x + threadIdx.x;

    for (int g = t0; g < MQKV * (DIM / 4); g += nthr) {
        int d4  = g & 255;
        int row = g >> 8;
        int b   = row >= SS;
        int s   = row - b * SS;
        const float* src;
        if (s < NPER)     src = pe + ((size_t)(b * NPER + s)) * DIM;
        else if (s < PFX) src = me + ((size_t)(b * NMEM + (s - NPER))) * DIM;
        else              src = x  + ((size_t)(b * LL   + (s - PFX)))  * DIM;
        float4 v = *reinterpret_cast<const float4*>(src + d4 * 4);
        ushort4 o; o.x = f2bf(v.x); o.y = f2bf(v.y); o.z = f2bf(v.z); o.w = f2bf(v.w);
        *reinterpret_cast<ushort4*>(xbf + (size_t)g * 4) = o;
    }
    for (int g = t0; g < NQKV * (DIM / 4); g += nthr) {
        int row = g >> 8;
        const float* src = (row < 1024) ? (Wq + (size_t)row * DIM)
                         : (row < 2048) ? (Wk + (size_t)(row - 1024) * DIM)
                         :                (Wv + (size_t)(row - 2048) * DIM);
        float4 v = *reinterpret_cast<const float4*>(src + (g & 255) * 4);
        ushort4 o; o.x = f2bf(v.x); o.y = f2bf(v.y); o.z = f2bf(v.z); o.w = f2bf(v.w);
        *reinterpret_cast<ushort4*>(wqkv + (size_t)g * 4) = o;
    }
    for (int g = t0; g < DIM * (DIM / 4); g += nthr) {
        float4 v = *reinterpret_cast<const float4*>(Wo + (size_t)g * 4);
        ushort4 o; o.x = f2bf(v.x); o.y = f2bf(v.y); o.z = f2bf(v.z); o.w = f2bf(v.w);
        *reinterpret_cast<ushort4*>(wobf + (size_t)g * 4) = o;
    }
    for (int i = t0; i < LL * 32; i += nthr) {
        int pos = i >> 5, fi = i & 31;
        float ang = (float)pos * exp2f(-(float)fi * 0.41524101186092029f);
        ropeC[i] = cosf(ang);
        ropeS[i] = sinf(ang);
    }
}

// ---------------------------------------------------------------------------
// 2-phase QKV GEMM, tile 128(M) x 64(N), BK=32, dbuf 24 KB LDS,
// grid 34x48 = 1632 blocks ~= 6.4 blocks/CU (launch_bounds(256,6)).
// Fourth rung of the occupancy ladder (1/CU=62.5, 2/CU=57.7, 3.2/CU=55.6 us).
// Geometry mirrors wo_gemm2p (8 MFMA/wave/K-step, measured-healthy shape).
// Same 2-phase loop, r14 clean row-major epilogue (bn 64-aligned -> 'which'
// still block-uniform).
// ---------------------------------------------------------------------------
__global__ __launch_bounds__(256, 6)
void qkv_gemm2p(const u16* __restrict__ X, const u16* __restrict__ Wq3,
                const float* __restrict__ ropeC, const float* __restrict__ ropeS,
                u16* __restrict__ qkvraw)
{
    __shared__ short Xs[2][128 * 32] __attribute__((aligned(16)));  // 16 KB
    __shared__ short Ws[2][64 * 32]  __attribute__((aligned(16)));  // 8 KB

    const int tid  = threadIdx.x;
    const int lane = tid & 63;
    const int wid  = tid >> 6;
    const int wr   = wid >> 1, wc = wid & 1;   // wr: W-col half (32), wc: X-row half (64)
    const int bm   = blockIdx.x * 128;
    const int bn   = blockIdx.y * 64;

    f32x4 acc[2][4];
#pragma unroll
    for (int m = 0; m < 2; ++m)
#pragma unroll
        for (int n = 0; n < 4; ++n) acc[m][n] = (f32x4)(0.f);

    const int r0 = wid * 32 + (lane >> 2);
    const int cc = (lane & 3) * 8;
    int ga0 = bm + r0;      if (ga0 > MQKV - 1) ga0 = MQKV - 1;
    int ga1 = bm + r0 + 16; if (ga1 > MQKV - 1) ga1 = MQKV - 1;
    const int gw = bn + wid * 16 + (lane >> 2);   // W row 0..63

#define STAGE2(buf, k0)                                                        \
    {                                                                          \
        gload_lds16(X + (size_t)ga0 * DIM + (k0) + cc, &Xs[buf][wid * 1024]);  \
        gload_lds16(X + (size_t)ga1 * DIM + (k0) + cc, &Xs[buf][wid * 1024 + 512]); \
        gload_lds16(Wq3 + (size_t)gw * DIM + (k0) + cc, &Ws[buf][wid * 512]);  \
    }

    STAGE2(0, 0);
    VMCNT0();
    BARRIER();

    for (int t = 0; t < 32; ++t) {
        const int cur = t & 1;
        int knext = (t + 1) * 32; if (knext >= DIM) knext = 0;  // dummy restage
        STAGE2(cur ^ 1, knext);

        bf16x8 wf[2], xf[4];
#pragma unroll
        for (int m = 0; m < 2; ++m)
            wf[m] = *reinterpret_cast<const bf16x8*>(
                &Ws[cur][(wr * 32 + m * 16 + (lane & 15)) * 32 + (lane >> 4) * 8]);
#pragma unroll
        for (int n = 0; n < 4; ++n)
            xf[n] = *reinterpret_cast<const bf16x8*>(
                &Xs[cur][(wc * 64 + n * 16 + (lane & 15)) * 32 + (lane >> 4) * 8]);

        __builtin_amdgcn_s_setprio(1);
#pragma unroll
        for (int m = 0; m < 2; ++m)
#pragma unroll
            for (int n = 0; n < 4; ++n)
                acc[m][n] = __builtin_amdgcn_mfma_f32_16x16x32_bf16(
                    wf[m], xf[n], acc[m][n], 0, 0, 0);
        __builtin_amdgcn_s_setprio(0);

        VMCNT0();
        BARRIER();
    }
#undef STAGE2

    // ---- epilogue: in-lane RoPE, clean row-major store (r14) ----
    const int cbase = bn + wr * 32 + ((lane >> 4) << 2);
    const int rbase = bm + wc * 64 + (lane & 15);
    const int which = bn >> 10;   // block-uniform: 0=Q 1=K 2=V

#pragma unroll
    for (int n = 0; n < 4; ++n) {
        const int row = rbase + n * 16;
        if (row >= MQKV) continue;
        const int b = row >= SS;
        const int s = row - b * SS;
        const bool rope = (which != 2) && (s >= PFX);
        const int pos = s - PFX;
#pragma unroll
        for (int m = 0; m < 2; ++m) {
            const int c0 = cbase + m * 16;
            float v0 = acc[m][n][0], v1 = acc[m][n][1];
            float v2 = acc[m][n][2], v3 = acc[m][n][3];
            if (rope) {
                const int dh = c0 & 63;
                float2 cs = *reinterpret_cast<const float2*>(ropeC + pos * 32 + (dh >> 1));
                float2 sn = *reinterpret_cast<const float2*>(ropeS + pos * 32 + (dh >> 1));
                float t0 = v0 * cs.x - v1 * sn.x;
                v1 = v0 * sn.x + v1 * cs.x; v0 = t0;
                float t2 = v2 * cs.y - v3 * sn.y;
                v3 = v2 * sn.y + v3 * cs.y; v2 = t2;
            }
            ushort4 o;
            o.x = f2bf(v0); o.y = f2bf(v1); o.z = f2bf(v2); o.w = f2bf(v3);
            *reinterpret_cast<ushort4*>(&qkvraw[(size_t)row * NQKV + c0]) = o;
        }
    }
}

// ---------------------------------------------------------------------------
// Wo GEMM, 2-phase dbuf (exact r19 kernel): tile 64x128, 512 blocks = 2/CU.
// ---------------------------------------------------------------------------
__global__ __launch_bounds__(256, 3)
void wo_gemm2p(const u16* __restrict__ A, const u16* __restrict__ Bw,
               float* __restrict__ outp)
{
    __shared__ short As[2][64 * 32]  __attribute__((aligned(16)));
    __shared__ short Bs[2][128 * 32] __attribute__((aligned(16)));

    const int tid  = threadIdx.x;
    const int lane = tid & 63;
    const int wid  = tid >> 6;
    const int wr   = wid >> 1, wc = wid & 1;
    const int bm   = blockIdx.x * 64;
    const int bn   = blockIdx.y * 128;

    f32x4 acc[4][2];
#pragma unroll
    for (int m = 0; m < 4; ++m)
#pragma unroll
        for (int n = 0; n < 2; ++n) acc[m][n] = (f32x4)(0.f);

    const int arow = bm + (tid >> 2);
    const int acol = (tid & 3) * 8;
    const int r0 = wid * 32 + (lane >> 2);
    const int cc = (lane & 3) * 8;
    const int gb0 = bn + r0, gb1 = bn + r0 + 16;

#define WSTAGE(buf, k0)                                                        \
    {                                                                          \
        gload_lds16(A + (size_t)arow * DIM + (k0) + acol, &As[buf][wid * 512]);\
        gload_lds16(Bw + (size_t)gb0 * DIM + (k0) + cc, &Bs[buf][wid * 1024]); \
        gload_lds16(Bw + (size_t)gb1 * DIM + (k0) + cc, &Bs[buf][wid * 1024 + 512]); \
    }

    WSTAGE(0, 0);
    VMCNT0();
    BARRIER();

    for (int t = 0; t < 32; ++t) {
        const int cur = t & 1;
        int knext = (t + 1) * 32; if (knext >= DIM) knext = 0;  // dummy restage
        WSTAGE(cur ^ 1, knext);

        bf16x8 wf[4], xf[2];
#pragma unroll
        for (int m = 0; m < 4; ++m)
            wf[m] = *reinterpret_cast<const bf16x8*>(
                &Bs[cur][(wr * 64 + m * 16 + (lane & 15)) * 32 + (lane >> 4) * 8]);
#pragma unroll
        for (int n = 0; n < 2; ++n)
            xf[n] = *reinterpret_cast<const bf16x8*>(
                &As[cur][(wc * 32 + n * 16 + (lane & 15)) * 32 + (lane >> 4) * 8]);

        __builtin_amdgcn_s_setprio(1);
#pragma unroll
        for (int m = 0; m < 4; ++m)
#pragma unroll
            for (int n = 0; n < 2; ++n)
                acc[m][n] = __builtin_amdgcn_mfma_f32_16x16x32_bf16(
                    wf[m], xf[n], acc[m][n], 0, 0, 0);
        __builtin_amdgcn_s_setprio(0);

        VMCNT0();
        BARRIER();
    }
#undef WSTAGE

    const int cbase = bn + wr * 64 + ((lane >> 4) << 2);
    const int rbase = bm + wc * 32 + (lane & 15);
#pragma unroll
    for (int n = 0; n < 2; ++n) {
        const int row = rbase + n * 16;
#pragma unroll
        for (int m = 0; m < 4; ++m) {
            const int c0 = cbase + m * 16;
            *reinterpret_cast<float4*>(&outp[(size_t)row * DIM + c0]) =
                make_float4(acc[m][n][0], acc[m][n][1], acc[m][n][2], acc[m][n][3]);
        }
    }
}

// ---------------------------------------------------------------------------
// MFMA flash attention (exact r14 kernel).
// ---------------------------------------------------------------------------
__device__ __forceinline__ void attn_load_tile(
    const u16* __restrict__ kb0, const u16* __restrict__ vb0,
    int j0, int tid, int vp, int vo,
    int4& k0r, int4& k1r, int4& v0r, int4& v1r)
{
    int key0 = tid >> 3,        o0 = tid & 7;
    int c1   = tid + 256;
    int key1 = c1 >> 3,         o1 = c1 & 7;
    int jg0 = j0 + key0; if (jg0 > SS - 1) jg0 = SS - 1;
    int jg1 = j0 + key1; if (jg1 > SS - 1) jg1 = SS - 1;
    k0r = *reinterpret_cast<const int4*>(kb0 + (size_t)jg0 * NQKV + o0 * 8);
    k1r = *reinterpret_cast<const int4*>(kb0 + (size_t)jg1 * NQKV + o1 * 8);
    int ja  = j0 + 2 * vp;     if (ja  > SS - 1) ja  = SS - 1;
    int jb2 = j0 + 2 * vp + 1; if (jb2 > SS - 1) jb2 = SS - 1;
    v0r = *reinterpret_cast<const int4*>(vb0 + (size_t)ja  * NQKV + vo * 8);
    v1r = *reinterpret_cast<const int4*>(vb0 + (size_t)jb2 * NQKV + vo * 8);
}

__global__ __launch_bounds__(256, 2)
void attn_mfma(const u16* __restrict__ qkvraw, u16* __restrict__ ctx)
{
    __shared__ u16 Ks[64 * 64] __attribute__((aligned(16)));
    __shared__ u16 Vt[64 * 64] __attribute__((aligned(16)));
    __shared__ u16 Ot[4][32 * 72] __attribute__((aligned(16)));

    const int tid  = threadIdx.x;
    const int lane = tid & 63;
    const int wv   = tid >> 6;
    const int h    = lane >> 5;
    const int ql   = lane & 31;

    const int bh   = blockIdx.y;
    const int b    = bh >> 4;
    const int head = bh & 15;
    int qt = blockIdx.x;
    if (b) qt = 15 - qt;
    const int q0  = qt * 128;
    const int q0w = q0 + 32 * wv;

    const u16* qrow = qkvraw + (size_t)(b * SS + PFX + q0w + ql) * NQKV + head * DHD;
    bf16x8 qf[4];
#pragma unroll
    for (int ks = 0; ks < 4; ++ks) {
        I4B8 t; t.i = *reinterpret_cast<const int4*>(qrow + ks * 16 + h * 8);
        qf[ks] = t.v;
    }

    f32x16 oa0 = (f32x16)(0.f), oa1 = (f32x16)(0.f);
    float m = -INFINITY, l = 0.f;

    const u16* kb0 = qkvraw + (size_t)b * SS * NQKV + 1024 + head * DHD;
    const u16* vb0 = qkvraw + (size_t)b * SS * NQKV + 2048 + head * DHD;

    const int ntiles   = (PFX + q0 + 128 + 63) / 64;
    const int wave_lim = PFX + q0w + 31;
    const int vp = tid & 31;
    const int vo = tid >> 5;

    int4 rk0, rk1, rv0, rv1;
    attn_load_tile(kb0, vb0, 0, tid, vp, vo, rk0, rk1, rv0, rv1);

    for (int kt = 0; kt < ntiles; ++kt) {
        const int j0 = kt * 64;

        {
            int key0 = tid >> 3, o0 = tid & 7;
            int c1 = tid + 256;
            int key1 = c1 >> 3, o1 = c1 & 7;
            *reinterpret_cast<int4*>((char*)Ks + ((key0 * 128 + o0 * 16) ^ ((key0 & 7) << 4))) = rk0;
            *reinterpret_cast<int4*>((char*)Ks + ((key1 * 128 + o1 * 16) ^ ((key1 & 7) << 4))) = rk1;
            const u16* pa = reinterpret_cast<const u16*>(&rv0);
            const u16* pb = reinterpret_cast<const u16*>(&rv1);
#pragma unroll
            for (int d = 0; d < 8; ++d) {
                u32 wpk = (u32)pa[d] | ((u32)pb[d] << 16);
                int dh = vo * 8 + d;
                *reinterpret_cast<u32*>((char*)Vt + ((dh * 128 + vp * 4) ^ ((d & 7) << 4))) = wpk;
            }
        }
        __syncthreads();

        int4 nk0, nk1, nv0, nv1;
        attn_load_tile(kb0, vb0, j0 + 64, tid, vp, vo, nk0, nk1, nv0, nv1);

        if (j0 <= wave_lim) {
            f32x16 s0 = (f32x16)(0.f), s1 = (f32x16)(0.f);
            __builtin_amdgcn_s_setprio(1);
#pragma unroll
            for (int ks = 0; ks < 4; ++ks) {
                I4B8 k0, k1;
                k0.i = *reinterpret_cast<const int4*>(
                    (const char*)Ks + (((ql) * 128 + ks * 32 + h * 16) ^ ((ql & 7) << 4)));
                k1.i = *reinterpret_cast<const int4*>(
                    (const char*)Ks + (((32 + ql) * 128 + ks * 32 + h * 16) ^ ((ql & 7) << 4)));
                s0 = __builtin_amdgcn_mfma_f32_32x32x16_bf16(k0.v, qf[ks], s0, 0, 0, 0);
                s1 = __builtin_amdgcn_mfma_f32_32x32x16_bf16(k1.v, qf[ks], s1, 0, 0, 0);
            }
            __builtin_amdgcn_s_setprio(0);
            float sv[32];
#pragma unroll
            for (int i = 0; i < 16; ++i) { sv[i] = s0[i] * 0.125f; sv[16 + i] = s1[i] * 0.125f; }
            if (j0 + 63 > PFX + q0w) {
                const int lim = PFX + q0w + ql - j0;
#pragma unroll
                for (int i = 0; i < 32; ++i) {
                    int koff = ((i >= 16) ? 32 : 0) + (i & 3) + 8 * ((i & 15) >> 2) + 4 * h;
                    if (koff > lim) sv[i] = -INFINITY;
                }
            }
            float mt = sv[0];
#pragma unroll
            for (int i = 1; i < 32; ++i) mt = fmaxf(mt, sv[i]);
            mt = fmaxf(mt, __shfl_xor(mt, 32));
            float mn = fmaxf(m, mt);
            float f = __expf(m - mn);
            m = mn;
            float ls = 0.f;
            u32 W0[8], W1[8];
#pragma unroll
            for (int i = 0; i < 8; ++i) {
                float pa = __expf(sv[2 * i] - m);
                float pb = __expf(sv[2 * i + 1] - m);
                ls += pa + pb;
                W0[i] = cvtpk(pa, pb);
            }
#pragma unroll
            for (int i = 0; i < 8; ++i) {
                float pa = __expf(sv[16 + 2 * i] - m);
                float pb = __expf(sv[16 + 2 * i + 1] - m);
                ls += pa + pb;
                W1[i] = cvtpk(pa, pb);
            }
            ls += __shfl_xor(ls, 32);
            l = l * f + ls;
#pragma unroll
            for (int i = 0; i < 16; ++i) { oa0[i] *= f; oa1[i] *= f; }

            __builtin_amdgcn_s_setprio(1);
#pragma unroll
            for (int ks = 0; ks < 4; ++ks) {
                const int a4 = (ks & 1) * 4;
                u32 A0, A1, A2, A3;
                if (ks < 2) { A0 = W0[a4]; A1 = W0[a4 + 1]; A2 = W0[a4 + 2]; A3 = W0[a4 + 3]; }
                else        { A0 = W1[a4]; A1 = W1[a4 + 1]; A2 = W1[a4 + 2]; A3 = W1[a4 + 3]; }
                asm volatile("v_permlane32_swap_b32 %0, %1" : "+v"(A0), "+v"(A2));
                asm volatile("v_permlane32_swap_b32 %0, %1" : "+v"(A1), "+v"(A3));
                I4B8 pf; pf.i = make_int4((int)A0, (int)A1, (int)A2, (int)A3);
                I4B8 vf0, vf1;
                vf0.i = *reinterpret_cast<const int4*>(
                    (const char*)Vt + (((ql) * 128 + ks * 32 + h * 16) ^ ((ql & 7) << 4)));
                vf1.i = *reinterpret_cast<const int4*>(
                    (const char*)Vt + (((32 + ql) * 128 + ks * 32 + h * 16) ^ ((ql & 7) << 4)));
                oa0 = __builtin_amdgcn_mfma_f32_32x32x16_bf16(vf0.v, pf.v, oa0, 0, 0, 0);
                oa1 = __builtin_amdgcn_mfma_f32_32x32x16_bf16(vf1.v, pf.v, oa1, 0, 0, 0);
            }
            __builtin_amdgcn_s_setprio(0);
        }
        __syncthreads();
        rk0 = nk0; rk1 = nk1; rv0 = nv0; rv1 = nv1;
    }

    const float inv = 1.f / l;
    u16* orow = &Ot[wv][ql * 72];
#pragma unroll
    for (int i = 0; i < 8; ++i) {
        u32 w0 = cvtpk(oa0[2 * i] * inv, oa0[2 * i + 1] * inv);
        u32 w1 = cvtpk(oa1[2 * i] * inv, oa1[2 * i + 1] * inv);
        int dh0 = ((2 * i) & 3) + 8 * ((2 * i) >> 2) + 4 * h;
        *reinterpret_cast<u32*>(&orow[dh0]) = w0;
        *reinterpret_cast<u32*>(&orow[32 + dh0]) = w1;
    }
    const int rr = lane >> 1, hh = lane & 1;
    const u16* src = &Ot[wv][rr * 72 + hh * 32];
    u16* dst = ctx + ((size_t)(b * LL + q0 + 32 * wv + rr)) * DIM + head * DHD + hh * 32;
#pragma unroll
    for (int i = 0; i < 4; ++i) {
        int4 t = *reinterpret_cast<const int4*>(src + i * 8);
        *reinterpret_cast<int4*>(dst + i * 8) = t;
    }
}

// ---------------------------------------------------------------------------
extern "C" void kernel_launch(void* const* d_in, const int* in_sizes, int n_in,
                              void* d_out, int out_size, void* d_ws, size_t ws_size,
                              hipStream_t stream)
{
    const float* x  = (const float*)d_in[0];
    const float* pe = (const float*)d_in[1];
    const float* me = (const float*)d_in[2];
    const float* Wq = (const float*)d_in[3];
    const float* Wk = (const float*)d_in[4];
    const float* Wv = (const float*)d_in[5];
    const float* Wo = (const float*)d_in[6];
    float* out = (float*)d_out;

    u16* xbf  = (u16*)d_ws;                           // 4256x1024
    u16* wqkv = xbf + (size_t)MQKV * DIM;             // 3072x1024
    u16* wobf = wqkv + (size_t)NQKV * DIM;            // 1024x1024
    float* ropeC = (float*)(wobf + (size_t)DIM * DIM);
    float* ropeS = ropeC + LL * 32;
    u16* qkvraw = (u16*)(ropeS + LL * 32);            // 4256x3072
    u16* ctx = qkvraw + (size_t)MQKV * NQKV;          // 4096x1024

    hipLaunchKernelGGL(prep_kernel, dim3(2048), dim3(256), 0, stream,
                       x, pe, me, Wq, Wk, Wv, Wo, xbf, wqkv, wobf, ropeC, ropeS);
    hipLaunchKernelGGL(qkv_gemm2p, dim3((MQKV + 127) / 128, NQKV / 64), dim3(256), 0, stream,
                       xbf, wqkv, ropeC, ropeS, qkvraw);
    hipLaunchKernelGGL(attn_mfma, dim3(16, BB * NH), dim3(256), 0, stream,
                       qkvraw, ctx);
    hipLaunchKernelGGL(wo_gemm2p, dim3(MOUT / 64, DIM / 128), dim3(256), 0, stream,
                       ctx, wobf, out);
}

// Round 21
// 128.075 us; speedup vs baseline: 1.1375x; 1.1375x over previous
//
#include <hip/hip_runtime.h>
#include <math.h>

#define BB    2
#define LL    2048
#define DIM   1024
#define NH    16
#define DHD   64
#define NPER  16
#define NMEM  64
#define PFX   80      // NPER + NMEM
#define SS    2128    // PFX + LL
#define MQKV  (BB*SS) // 4256
#define NQKV  3072
#define MOUT  (BB*LL) // 4096

typedef __attribute__((ext_vector_type(4)))  float f32x4;
typedef __attribute__((ext_vector_type(16))) float f32x16;
typedef __attribute__((ext_vector_type(8)))  short bf16x8;
typedef unsigned short u16;
typedef unsigned int   u32;

union I4B8 { int4 i; bf16x8 v; };

__device__ __forceinline__ u16 f2bf(float x) {
    union { float f; u32 u; } v; v.f = x;
    return (u16)((v.u + 0x7fffu + ((v.u >> 16) & 1u)) >> 16);
}
__device__ __forceinline__ u32 cvtpk(float lo, float hi) {
    u32 r; asm("v_cvt_pk_bf16_f32 %0, %1, %2" : "=v"(r) : "v"(lo), "v"(hi));
    return r;
}
__device__ __forceinline__ void gload_lds16(const void* g, void* l) {
    __builtin_amdgcn_global_load_lds(
        (__attribute__((address_space(1))) void*)(g),
        (__attribute__((address_space(3))) void*)(l), 16, 0, 0);
}

#define BARRIER()  __builtin_amdgcn_s_barrier()
#define VMCNT0()   asm volatile("s_waitcnt vmcnt(0)")

// ---------------------------------------------------------------------------
// Prep: fp32 -> bf16 conversions + RoPE tables
// ---------------------------------------------------------------------------
__global__ __launch_bounds__(256)
void prep_kernel(const float* __restrict__ x,  const float* __restrict__ pe,
                 const float* __restrict__ me, const float* __restrict__ Wq,
                 const float* __restrict__ Wk, const float* __restrict__ Wv,
                 const float* __restrict__ Wo,
                 u16* __restrict__ xbf, u16* __restrict__ wqkv,
                 u16* __restrict__ wobf,
                 float* __restrict__ ropeC, float* __restrict__ ropeS)
{
    const int nthr = gridDim.x * blockDim.x;
    const int t0   = blockIdx.x * blockDim.x + threadIdx.x;

    for (int g = t0; g < MQKV * (DIM / 4); g += nthr) {
        int d4  = g & 255;
        int row = g >> 8;
        int b   = row >= SS;
        int s   = row - b * SS;
        const float* src;
        if (s < NPER)     src = pe + ((size_t)(b * NPER + s)) * DIM;
        else if (s < PFX) src = me + ((size_t)(b * NMEM + (s - NPER))) * DIM;
        else              src = x  + ((size_t)(b * LL   + (s - PFX)))  * DIM;
        float4 v = *reinterpret_cast<const float4*>(src + d4 * 4);
        ushort4 o; o.x = f2bf(v.x); o.y = f2bf(v.y); o.z = f2bf(v.z); o.w = f2bf(v.w);
        *reinterpret_cast<ushort4*>(xbf + (size_t)g * 4) = o;
    }
    for (int g = t0; g < NQKV * (DIM / 4); g += nthr) {
        int row = g >> 8;
        const float* src = (row < 1024) ? (Wq + (size_t)row * DIM)
                         : (row < 2048) ? (Wk + (size_t)(row - 1024) * DIM)
                         :                (Wv + (size_t)(row - 2048) * DIM);
        float4 v = *reinterpret_cast<const float4*>(src + (g & 255) * 4);
        ushort4 o; o.x = f2bf(v.x); o.y = f2bf(v.y); o.z = f2bf(v.z); o.w = f2bf(v.w);
        *reinterpret_cast<ushort4*>(wqkv + (size_t)g * 4) = o;
    }
    for (int g = t0; g < DIM * (DIM / 4); g += nthr) {
        float4 v = *reinterpret_cast<const float4*>(Wo + (size_t)g * 4);
        ushort4 o; o.x = f2bf(v.x); o.y = f2bf(v.y); o.z = f2bf(v.z); o.w = f2bf(v.w);
        *reinterpret_cast<ushort4*>(wobf + (size_t)g * 4) = o;
    }
    for (int i = t0; i < LL * 32; i += nthr) {
        int pos = i >> 5, fi = i & 31;
        float ang = (float)pos * exp2f(-(float)fi * 0.41524101186092029f);
        ropeC[i] = cosf(ang);
        ropeS[i] = sinf(ang);
    }
}

// ---------------------------------------------------------------------------
// 2-phase QKV GEMM (exact r18/r19 kernel): 128x128 tile, BK=32, dbuf 32 KB,
// 3 blocks/CU, grid 34x24 = 816 blocks, r14 clean row-major epilogue.
// (r20's 128x64 @6.4/CU regressed: occupancy ladder saturated at this rung.)
// ---------------------------------------------------------------------------
__global__ __launch_bounds__(256, 3)
void qkv_gemm2p(const u16* __restrict__ X, const u16* __restrict__ Wq3,
                const float* __restrict__ ropeC, const float* __restrict__ ropeS,
                u16* __restrict__ qkvraw)
{
    __shared__ short Xs[2][128 * 32] __attribute__((aligned(16)));  // 16 KB
    __shared__ short Ws[2][128 * 32] __attribute__((aligned(16)));  // 16 KB

    const int tid  = threadIdx.x;
    const int lane = tid & 63;
    const int wid  = tid >> 6;
    const int wr   = wid >> 1, wc = wid & 1;
    const int bm   = blockIdx.x * 128;
    const int bn   = blockIdx.y * 128;

    f32x4 acc[4][4];
#pragma unroll
    for (int m = 0; m < 4; ++m)
#pragma unroll
        for (int n = 0; n < 4; ++n) acc[m][n] = (f32x4)(0.f);

    const int r0 = wid * 32 + (lane >> 2);
    const int cc = (lane & 3) * 8;
    int ga0 = bm + r0;      if (ga0 > MQKV - 1) ga0 = MQKV - 1;
    int ga1 = bm + r0 + 16; if (ga1 > MQKV - 1) ga1 = MQKV - 1;
    const int gb0 = bn + r0, gb1 = bn + r0 + 16;

#define STAGE2(buf, k0)                                                        \
    {                                                                          \
        gload_lds16(X + (size_t)ga0 * DIM + (k0) + cc, &Xs[buf][wid * 1024]);  \
        gload_lds16(X + (size_t)ga1 * DIM + (k0) + cc, &Xs[buf][wid * 1024 + 512]); \
        gload_lds16(Wq3 + (size_t)gb0 * DIM + (k0) + cc, &Ws[buf][wid * 1024]);\
        gload_lds16(Wq3 + (size_t)gb1 * DIM + (k0) + cc, &Ws[buf][wid * 1024 + 512]); \
    }

    STAGE2(0, 0);
    VMCNT0();
    BARRIER();

    for (int t = 0; t < 32; ++t) {
        const int cur = t & 1;
        int knext = (t + 1) * 32; if (knext >= DIM) knext = 0;  // dummy restage
        STAGE2(cur ^ 1, knext);

        bf16x8 wf[4], xf[4];
#pragma unroll
        for (int m = 0; m < 4; ++m)
            wf[m] = *reinterpret_cast<const bf16x8*>(
                &Ws[cur][(wr * 64 + m * 16 + (lane & 15)) * 32 + (lane >> 4) * 8]);
#pragma unroll
        for (int n = 0; n < 4; ++n)
            xf[n] = *reinterpret_cast<const bf16x8*>(
                &Xs[cur][(wc * 64 + n * 16 + (lane & 15)) * 32 + (lane >> 4) * 8]);

        __builtin_amdgcn_s_setprio(1);
#pragma unroll
        for (int m = 0; m < 4; ++m)
#pragma unroll
            for (int n = 0; n < 4; ++n)
                acc[m][n] = __builtin_amdgcn_mfma_f32_16x16x32_bf16(
                    wf[m], xf[n], acc[m][n], 0, 0, 0);
        __builtin_amdgcn_s_setprio(0);

        VMCNT0();
        BARRIER();
    }
#undef STAGE2

    const int cbase = bn + wr * 64 + ((lane >> 4) << 2);
    const int rbase = bm + wc * 64 + (lane & 15);
    const int which = bn >> 10;

#pragma unroll
    for (int n = 0; n < 4; ++n) {
        const int row = rbase + n * 16;
        if (row >= MQKV) continue;
        const int b = row >= SS;
        const int s = row - b * SS;
        const bool rope = (which != 2) && (s >= PFX);
        const int pos = s - PFX;
#pragma unroll
        for (int m = 0; m < 4; ++m) {
            const int c0 = cbase + m * 16;
            float v0 = acc[m][n][0], v1 = acc[m][n][1];
            float v2 = acc[m][n][2], v3 = acc[m][n][3];
            if (rope) {
                const int dh = c0 & 63;
                float2 cs = *reinterpret_cast<const float2*>(ropeC + pos * 32 + (dh >> 1));
                float2 sn = *reinterpret_cast<const float2*>(ropeS + pos * 32 + (dh >> 1));
                float t0 = v0 * cs.x - v1 * sn.x;
                v1 = v0 * sn.x + v1 * cs.x; v0 = t0;
                float t2 = v2 * cs.y - v3 * sn.y;
                v3 = v2 * sn.y + v3 * cs.y; v2 = t2;
            }
            ushort4 o;
            o.x = f2bf(v0); o.y = f2bf(v1); o.z = f2bf(v2); o.w = f2bf(v3);
            *reinterpret_cast<ushort4*>(&qkvraw[(size_t)row * NQKV + c0]) = o;
        }
    }
}

// ---------------------------------------------------------------------------
// Wo GEMM, 2-phase dbuf (exact r19 kernel): tile 64x128, 512 blocks = 2/CU.
// ---------------------------------------------------------------------------
__global__ __launch_bounds__(256, 3)
void wo_gemm2p(const u16* __restrict__ A, const u16* __restrict__ Bw,
               float* __restrict__ outp)
{
    __shared__ short As[2][64 * 32]  __attribute__((aligned(16)));
    __shared__ short Bs[2][128 * 32] __attribute__((aligned(16)));

    const int tid  = threadIdx.x;
    const int lane = tid & 63;
    const int wid  = tid >> 6;
    const int wr   = wid >> 1, wc = wid & 1;
    const int bm   = blockIdx.x * 64;
    const int bn   = blockIdx.y * 128;

    f32x4 acc[4][2];
#pragma unroll
    for (int m = 0; m < 4; ++m)
#pragma unroll
        for (int n = 0; n < 2; ++n) acc[m][n] = (f32x4)(0.f);

    const int arow = bm + (tid >> 2);
    const int acol = (tid & 3) * 8;
    const int r0 = wid * 32 + (lane >> 2);
    const int cc = (lane & 3) * 8;
    const int gb0 = bn + r0, gb1 = bn + r0 + 16;

#define WSTAGE(buf, k0)                                                        \
    {                                                                          \
        gload_lds16(A + (size_t)arow * DIM + (k0) + acol, &As[buf][wid * 512]);\
        gload_lds16(Bw + (size_t)gb0 * DIM + (k0) + cc, &Bs[buf][wid * 1024]); \
        gload_lds16(Bw + (size_t)gb1 * DIM + (k0) + cc, &Bs[buf][wid * 1024 + 512]); \
    }

    WSTAGE(0, 0);
    VMCNT0();
    BARRIER();

    for (int t = 0; t < 32; ++t) {
        const int cur = t & 1;
        int knext = (t + 1) * 32; if (knext >= DIM) knext = 0;  // dummy restage
        WSTAGE(cur ^ 1, knext);

        bf16x8 wf[4], xf[2];
#pragma unroll
        for (int m = 0; m < 4; ++m)
            wf[m] = *reinterpret_cast<const bf16x8*>(
                &Bs[cur][(wr * 64 + m * 16 + (lane & 15)) * 32 + (lane >> 4) * 8]);
#pragma unroll
        for (int n = 0; n < 2; ++n)
            xf[n] = *reinterpret_cast<const bf16x8*>(
                &As[cur][(wc * 32 + n * 16 + (lane & 15)) * 32 + (lane >> 4) * 8]);

        __builtin_amdgcn_s_setprio(1);
#pragma unroll
        for (int m = 0; m < 4; ++m)
#pragma unroll
            for (int n = 0; n < 2; ++n)
                acc[m][n] = __builtin_amdgcn_mfma_f32_16x16x32_bf16(
                    wf[m], xf[n], acc[m][n], 0, 0, 0);
        __builtin_amdgcn_s_setprio(0);

        VMCNT0();
        BARRIER();
    }
#undef WSTAGE

    const int cbase = bn + wr * 64 + ((lane >> 4) << 2);
    const int rbase = bm + wc * 32 + (lane & 15);
#pragma unroll
    for (int n = 0; n < 2; ++n) {
        const int row = rbase + n * 16;
#pragma unroll
        for (int m = 0; m < 4; ++m) {
            const int c0 = cbase + m * 16;
            *reinterpret_cast<float4*>(&outp[(size_t)row * DIM + c0]) =
                make_float4(acc[m][n][0], acc[m][n][1], acc[m][n][2], acc[m][n][3]);
        }
    }
}

// ---------------------------------------------------------------------------
// MFMA flash attention (exact r14 kernel).
// ---------------------------------------------------------------------------
__device__ __forceinline__ void attn_load_tile(
    const u16* __restrict__ kb0, const u16* __restrict__ vb0,
    int j0, int tid, int vp, int vo,
    int4& k0r, int4& k1r, int4& v0r, int4& v1r)
{
    int key0 = tid >> 3,        o0 = tid & 7;
    int c1   = tid + 256;
    int key1 = c1 >> 3,         o1 = c1 & 7;
    int jg0 = j0 + key0; if (jg0 > SS - 1) jg0 = SS - 1;
    int jg1 = j0 + key1; if (jg1 > SS - 1) jg1 = SS - 1;
    k0r = *reinterpret_cast<const int4*>(kb0 + (size_t)jg0 * NQKV + o0 * 8);
    k1r = *reinterpret_cast<const int4*>(kb0 + (size_t)jg1 * NQKV + o1 * 8);
    int ja  = j0 + 2 * vp;     if (ja  > SS - 1) ja  = SS - 1;
    int jb2 = j0 + 2 * vp + 1; if (jb2 > SS - 1) jb2 = SS - 1;
    v0r = *reinterpret_cast<const int4*>(vb0 + (size_t)ja  * NQKV + vo * 8);
    v1r = *reinterpret_cast<const int4*>(vb0 + (size_t)jb2 * NQKV + vo * 8);
}

__global__ __launch_bounds__(256, 2)
void attn_mfma(const u16* __restrict__ qkvraw, u16* __restrict__ ctx)
{
    __shared__ u16 Ks[64 * 64] __attribute__((aligned(16)));
    __shared__ u16 Vt[64 * 64] __attribute__((aligned(16)));
    __shared__ u16 Ot[4][32 * 72] __attribute__((aligned(16)));

    const int tid  = threadIdx.x;
    const int lane = tid & 63;
    const int wv   = tid >> 6;
    const int h    = lane >> 5;
    const int ql   = lane & 31;

    const int bh   = blockIdx.y;
    const int b    = bh >> 4;
    const int head = bh & 15;
    int qt = blockIdx.x;
    if (b) qt = 15 - qt;
    const int q0  = qt * 128;
    const int q0w = q0 + 32 * wv;

    const u16* qrow = qkvraw + (size_t)(b * SS + PFX + q0w + ql) * NQKV + head * DHD;
    bf16x8 qf[4];
#pragma unroll
    for (int ks = 0; ks < 4; ++ks) {
        I4B8 t; t.i = *reinterpret_cast<const int4*>(qrow + ks * 16 + h * 8);
        qf[ks] = t.v;
    }

    f32x16 oa0 = (f32x16)(0.f), oa1 = (f32x16)(0.f);
    float m = -INFINITY, l = 0.f;

    const u16* kb0 = qkvraw + (size_t)b * SS * NQKV + 1024 + head * DHD;
    const u16* vb0 = qkvraw + (size_t)b * SS * NQKV + 2048 + head * DHD;

    const int ntiles   = (PFX + q0 + 128 + 63) / 64;
    const int wave_lim = PFX + q0w + 31;
    const int vp = tid & 31;
    const int vo = tid >> 5;

    int4 rk0, rk1, rv0, rv1;
    attn_load_tile(kb0, vb0, 0, tid, vp, vo, rk0, rk1, rv0, rv1);

    for (int kt = 0; kt < ntiles; ++kt) {
        const int j0 = kt * 64;

        {
            int key0 = tid >> 3, o0 = tid & 7;
            int c1 = tid + 256;
            int key1 = c1 >> 3, o1 = c1 & 7;
            *reinterpret_cast<int4*>((char*)Ks + ((key0 * 128 + o0 * 16) ^ ((key0 & 7) << 4))) = rk0;
            *reinterpret_cast<int4*>((char*)Ks + ((key1 * 128 + o1 * 16) ^ ((key1 & 7) << 4))) = rk1;
            const u16* pa = reinterpret_cast<const u16*>(&rv0);
            const u16* pb = reinterpret_cast<const u16*>(&rv1);
#pragma unroll
            for (int d = 0; d < 8; ++d) {
                u32 wpk = (u32)pa[d] | ((u32)pb[d] << 16);
                int dh = vo * 8 + d;
                *reinterpret_cast<u32*>((char*)Vt + ((dh * 128 + vp * 4) ^ ((d & 7) << 4))) = wpk;
            }
        }
        __syncthreads();

        int4 nk0, nk1, nv0, nv1;
        attn_load_tile(kb0, vb0, j0 + 64, tid, vp, vo, nk0, nk1, nv0, nv1);

        if (j0 <= wave_lim) {
            f32x16 s0 = (f32x16)(0.f), s1 = (f32x16)(0.f);
            __builtin_amdgcn_s_setprio(1);
#pragma unroll
            for (int ks = 0; ks < 4; ++ks) {
                I4B8 k0, k1;
                k0.i = *reinterpret_cast<const int4*>(
                    (const char*)Ks + (((ql) * 128 + ks * 32 + h * 16) ^ ((ql & 7) << 4)));
                k1.i = *reinterpret_cast<const int4*>(
                    (const char*)Ks + (((32 + ql) * 128 + ks * 32 + h * 16) ^ ((ql & 7) << 4)));
                s0 = __builtin_amdgcn_mfma_f32_32x32x16_bf16(k0.v, qf[ks], s0, 0, 0, 0);
                s1 = __builtin_amdgcn_mfma_f32_32x32x16_bf16(k1.v, qf[ks], s1, 0, 0, 0);
            }
            __builtin_amdgcn_s_setprio(0);
            float sv[32];
#pragma unroll
            for (int i = 0; i < 16; ++i) { sv[i] = s0[i] * 0.125f; sv[16 + i] = s1[i] * 0.125f; }
            if (j0 + 63 > PFX + q0w) {
                const int lim = PFX + q0w + ql - j0;
#pragma unroll
                for (int i = 0; i < 32; ++i) {
                    int koff = ((i >= 16) ? 32 : 0) + (i & 3) + 8 * ((i & 15) >> 2) + 4 * h;
                    if (koff > lim) sv[i] = -INFINITY;
                }
            }
            float mt = sv[0];
#pragma unroll
            for (int i = 1; i < 32; ++i) mt = fmaxf(mt, sv[i]);
            mt = fmaxf(mt, __shfl_xor(mt, 32));
            float mn = fmaxf(m, mt);
            float f = __expf(m - mn);
            m = mn;
            float ls = 0.f;
            u32 W0[8], W1[8];
#pragma unroll
            for (int i = 0; i < 8; ++i) {
                float pa = __expf(sv[2 * i] - m);
                float pb = __expf(sv[2 * i + 1] - m);
                ls += pa + pb;
                W0[i] = cvtpk(pa, pb);
            }
#pragma unroll
            for (int i = 0; i < 8; ++i) {
                float pa = __expf(sv[16 + 2 * i] - m);
                float pb = __expf(sv[16 + 2 * i + 1] - m);
                ls += pa + pb;
                W1[i] = cvtpk(pa, pb);
            }
            ls += __shfl_xor(ls, 32);
            l = l * f + ls;
#pragma unroll
            for (int i = 0; i < 16; ++i) { oa0[i] *= f; oa1[i] *= f; }

            __builtin_amdgcn_s_setprio(1);
#pragma unroll
            for (int ks = 0; ks < 4; ++ks) {
                const int a4 = (ks & 1) * 4;
                u32 A0, A1, A2, A3;
                if (ks < 2) { A0 = W0[a4]; A1 = W0[a4 + 1]; A2 = W0[a4 + 2]; A3 = W0[a4 + 3]; }
                else        { A0 = W1[a4]; A1 = W1[a4 + 1]; A2 = W1[a4 + 2]; A3 = W1[a4 + 3]; }
                asm volatile("v_permlane32_swap_b32 %0, %1" : "+v"(A0), "+v"(A2));
                asm volatile("v_permlane32_swap_b32 %0, %1" : "+v"(A1), "+v"(A3));
                I4B8 pf; pf.i = make_int4((int)A0, (int)A1, (int)A2, (int)A3);
                I4B8 vf0, vf1;
                vf0.i = *reinterpret_cast<const int4*>(
                    (const char*)Vt + (((ql) * 128 + ks * 32 + h * 16) ^ ((ql & 7) << 4)));
                vf1.i = *reinterpret_cast<const int4*>(
                    (const char*)Vt + (((32 + ql) * 128 + ks * 32 + h * 16) ^ ((ql & 7) << 4)));
                oa0 = __builtin_amdgcn_mfma_f32_32x32x16_bf16(vf0.v, pf.v, oa0, 0, 0, 0);
                oa1 = __builtin_amdgcn_mfma_f32_32x32x16_bf16(vf1.v, pf.v, oa1, 0, 0, 0);
            }
            __builtin_amdgcn_s_setprio(0);
        }
        __syncthreads();
        rk0 = nk0; rk1 = nk1; rv0 = nv0; rv1 = nv1;
    }

    const float inv = 1.f / l;
    u16* orow = &Ot[wv][ql * 72];
#pragma unroll
    for (int i = 0; i < 8; ++i) {
        u32 w0 = cvtpk(oa0[2 * i] * inv, oa0[2 * i + 1] * inv);
        u32 w1 = cvtpk(oa1[2 * i] * inv, oa1[2 * i + 1] * inv);
        int dh0 = ((2 * i) & 3) + 8 * ((2 * i) >> 2) + 4 * h;
        *reinterpret_cast<u32*>(&orow[dh0]) = w0;
        *reinterpret_cast<u32*>(&orow[32 + dh0]) = w1;
    }
    const int rr = lane >> 1, hh = lane & 1;
    const u16* src = &Ot[wv][rr * 72 + hh * 32];
    u16* dst = ctx + ((size_t)(b * LL + q0 + 32 * wv + rr)) * DIM + head * DHD + hh * 32;
#pragma unroll
    for (int i = 0; i < 4; ++i) {
        int4 t = *reinterpret_cast<const int4*>(src + i * 8);
        *reinterpret_cast<int4*>(dst + i * 8) = t;
    }
}

// ---------------------------------------------------------------------------
extern "C" void kernel_launch(void* const* d_in, const int* in_sizes, int n_in,
                              void* d_out, int out_size, void* d_ws, size_t ws_size,
                              hipStream_t stream)
{
    const float* x  = (const float*)d_in[0];
    const float* pe = (const float*)d_in[1];
    const float* me = (const float*)d_in[2];
    const float* Wq = (const float*)d_in[3];
    const float* Wk = (const float*)d_in[4];
    const float* Wv = (const float*)d_in[5];
    const float* Wo = (const float*)d_in[6];
    float* out = (float*)d_out;

    u16* xbf  = (u16*)d_ws;                           // 4256x1024
    u16* wqkv = xbf + (size_t)MQKV * DIM;             // 3072x1024
    u16* wobf = wqkv + (size_t)NQKV * DIM;            // 1024x1024
    float* ropeC = (float*)(wobf + (size_t)DIM * DIM);
    float* ropeS = ropeC + LL * 32;
    u16* qkvraw = (u16*)(ropeS + LL * 32);            // 4256x3072
    u16* ctx = qkvraw + (size_t)MQKV * NQKV;          // 4096x1024

    hipLaunchKernelGGL(prep_kernel, dim3(2048), dim3(256), 0, stream,
                       x, pe, me, Wq, Wk, Wv, Wo, xbf, wqkv, wobf, ropeC, ropeS);
    hipLaunchKernelGGL(qkv_gemm2p, dim3((MQKV + 127) / 128, NQKV / 128), dim3(256), 0, stream,
                       xbf, wqkv, ropeC, ropeS, qkvraw);
    hipLaunchKernelGGL(attn_mfma, dim3(16, BB * NH), dim3(256), 0, stream,
                       qkvraw, ctx);
    hipLaunchKernelGGL(wo_gemm2p, dim3(MOUT / 64, DIM / 128), dim3(256), 0, stream,
                       ctx, wobf, out);
}